// Round 4
// baseline (154.971 us; speedup 1.0000x reference)
//
#include <hip/hip_runtime.h>

#define F_IN 128
#define CH   128

typedef __attribute__((ext_vector_type(8))) short bf16x8;
typedef __attribute__((ext_vector_type(4))) float f32x4;
typedef __attribute__((ext_vector_type(4))) unsigned u32x4;

// f32 -> bf16 round-to-nearest-even
static __device__ __forceinline__ ushort f2b(float f) {
  union { float f; unsigned u; } v; v.f = f;
  const unsigned u = v.u;
  return (ushort)((u + 0x7FFFu + ((u >> 16) & 1u)) >> 16);
}

// ---------------------------------------------------------------------------
// Phase 1 (fused): blocks [0, gemm_blocks) do XW = X @ W via bf16 MFMA,
//   then quantize each output row to int8 (offset-binary, per-node scale
//   s[r] = rowmax/127) -> 12.8 MB table + 400 KB scales.
// blocks [gemm_blocks, ...) do row_ptr[r] = lower_bound(edge_row, r).
// mfma_f32_16x16x32_bf16 layouts (guide §3, m89-verified):
//   A frag: row = lane&15, k = (lane>>4)*8 + j
//   B frag: col = lane&15, k = (lane>>4)*8 + j
//   C/D   : col = lane&15, row = (lane>>4)*4 + reg
// ---------------------------------------------------------------------------
__global__ __launch_bounds__(512) void gemm_rowptr_fused(
    const float* __restrict__ x, const float* __restrict__ w,
    unsigned char* __restrict__ xwq, float* __restrict__ scale,
    const int* __restrict__ edge_row, int* __restrict__ row_ptr,
    int n, int n_edges, int gemm_blocks) {
  __shared__ __align__(16) ushort Wt[F_IN * CH];  // W^T, swizzled, 32 KB
  const int t = threadIdx.x;

  if ((int)blockIdx.x >= gemm_blocks) {
    // ---- rowptr tail blocks: CSR offsets from sorted edge_row ----
    const int r = ((int)blockIdx.x - gemm_blocks) * 512 + t;
    if (r <= n) {
      int lo = 0, hi = n_edges;
      while (lo < hi) {
        const int mid = (lo + hi) >> 1;
        if (edge_row[mid] < r) lo = mid + 1; else hi = mid;
      }
      row_ptr[r] = lo;
    }
    return;
  }

  // ---- GEMM blocks ----
  // stage W^T as bf16 with XOR swizzle: byte ^= (col&7)<<4
  for (int i = t; i < (F_IN * CH) / 4; i += 512) {
    const int k  = i >> 5;          // 0..127
    const int n4 = (i & 31) << 2;   // 0,4,...,124
    const f32x4 wv = *(const f32x4*)&w[k * CH + n4];
#pragma unroll
    for (int q = 0; q < 4; ++q) {
      const int nn = n4 + q;
      const int byte = (nn * 256 + k * 2) ^ ((nn & 7) << 4);
      *(ushort*)((char*)Wt + byte) = f2b(wv[q]);
    }
  }
  __syncthreads();

  const int wave = t >> 6, lane = t & 63;
  const int R0   = blockIdx.x * 128 + wave * 16;
  const int arow = R0 + (lane & 15);
  const int kgrp = (lane >> 4) * 8;

  // A fragments (4 K-steps), f32->bf16 in-register; x is read-once -> nt loads
  bf16x8 a[4];
#pragma unroll
  for (int s = 0; s < 4; ++s) {
    if (arow < n) {
      const f32x4 p0 = __builtin_nontemporal_load(
          (const f32x4*)&x[arow * F_IN + s * 32 + kgrp]);
      const f32x4 p1 = __builtin_nontemporal_load(
          (const f32x4*)&x[arow * F_IN + s * 32 + kgrp + 4]);
#pragma unroll
      for (int j = 0; j < 4; ++j) {
        a[s][j]     = (short)f2b(p0[j]);
        a[s][j + 4] = (short)f2b(p1[j]);
      }
    } else {
#pragma unroll
      for (int j = 0; j < 8; ++j) a[s][j] = (short)0;
    }
  }

  f32x4 acc[8];
#pragma unroll
  for (int t8 = 0; t8 < 8; ++t8) acc[t8] = (f32x4){0.f, 0.f, 0.f, 0.f};

#pragma unroll
  for (int t8 = 0; t8 < 8; ++t8) {
    const int col = t8 * 16 + (lane & 15);
#pragma unroll
    for (int s = 0; s < 4; ++s) {
      const int byte = (col * 256 + (s * 32 + kgrp) * 2) ^ ((col & 7) << 4);
      const bf16x8 b = *(const bf16x8*)((const char*)Wt + byte);
      acc[t8] = __builtin_amdgcn_mfma_f32_16x16x32_bf16(a[s], b, acc[t8], 0, 0, 0);
    }
  }

  // Epilogue: per-row absmax (shfl over the 16 channel-lanes) -> int8 quant.
  const int li = lane & 15;
  const int r0 = R0 + (lane >> 4) * 4;
#pragma unroll
  for (int i = 0; i < 4; ++i) {
    const int rr = r0 + i;
    float m = 0.f;
#pragma unroll
    for (int t8 = 0; t8 < 8; ++t8) m = fmaxf(m, fabsf(acc[t8][i]));
    m = fmaxf(m, __shfl_xor(m, 1));
    m = fmaxf(m, __shfl_xor(m, 2));
    m = fmaxf(m, __shfl_xor(m, 4));
    m = fmaxf(m, __shfl_xor(m, 8));
    const float inv = (m > 1e-20f) ? 127.f / m : 0.f;
    if (rr < n) {
      if (li == 0) scale[rr] = m * (1.f / 127.f);
#pragma unroll
      for (int t8 = 0; t8 < 8; ++t8) {
        // |acc|*inv <= 127 by construction; +128 -> [1,255], no clamp needed
        const float q = rintf(acc[t8][i] * inv) + 128.f;
        xwq[rr * CH + t8 * 16 + li] = (unsigned char)q;
      }
    }
  }
}

// ---------------------------------------------------------------------------
// Phase 2: SpMM on the int8 table. GRID-STRIDE over rows (2048 blocks -> CP
// dispatch no longer a factor; ~12 rows/wave), one wave per row at a time.
// 64-edge superblock with EARLY-EXIT on empty sub-iters (wave-uniform break:
// mean degree 32 -> only ~4.3 of 8 sub-iters run, was always 8).
//   * meta: each lane owns ONE edge -> 2 coalesced loads + 1 scale gather
//     per 64 edges. vp = val*scale[col], distributed via __shfl.
//   * row gathers: 8 lanes x u32x4 (16B) per 128B int8 row.
// -128 offset folded into scalar S (full-wave reduced). Butterfly over the
// 8 edge-subgroups (xor 8/16/32) at the end; lanes with g8==0 write out.
// ---------------------------------------------------------------------------
#define ACC16(U, V)                                                     \
  do {                                                                  \
    acc[ 0] = fmaf((V), (float)((U)[0]         & 0xFFu), acc[ 0]);      \
    acc[ 1] = fmaf((V), (float)(((U)[0] >>  8) & 0xFFu), acc[ 1]);      \
    acc[ 2] = fmaf((V), (float)(((U)[0] >> 16) & 0xFFu), acc[ 2]);      \
    acc[ 3] = fmaf((V), (float)((U)[0] >> 24),           acc[ 3]);      \
    acc[ 4] = fmaf((V), (float)((U)[1]         & 0xFFu), acc[ 4]);      \
    acc[ 5] = fmaf((V), (float)(((U)[1] >>  8) & 0xFFu), acc[ 5]);      \
    acc[ 6] = fmaf((V), (float)(((U)[1] >> 16) & 0xFFu), acc[ 6]);      \
    acc[ 7] = fmaf((V), (float)((U)[1] >> 24),           acc[ 7]);      \
    acc[ 8] = fmaf((V), (float)((U)[2]         & 0xFFu), acc[ 8]);      \
    acc[ 9] = fmaf((V), (float)(((U)[2] >>  8) & 0xFFu), acc[ 9]);      \
    acc[10] = fmaf((V), (float)(((U)[2] >> 16) & 0xFFu), acc[10]);      \
    acc[11] = fmaf((V), (float)((U)[2] >> 24),           acc[11]);      \
    acc[12] = fmaf((V), (float)((U)[3]         & 0xFFu), acc[12]);      \
    acc[13] = fmaf((V), (float)(((U)[3] >>  8) & 0xFFu), acc[13]);      \
    acc[14] = fmaf((V), (float)(((U)[3] >> 16) & 0xFFu), acc[14]);      \
    acc[15] = fmaf((V), (float)((U)[3] >> 24),           acc[15]);      \
  } while (0)

__global__ __launch_bounds__(256) void spmm_rowwave(
    const unsigned char* __restrict__ xwq, const float* __restrict__ scale,
    const float* __restrict__ edge_val, const int* __restrict__ edge_col,
    const int* __restrict__ row_ptr, const float* __restrict__ bias,
    float* __restrict__ out, int n) {
  const int nwaves = (int)((gridDim.x * blockDim.x) >> 6);
  const int wid0   = (int)((blockIdx.x * blockDim.x + threadIdx.x) >> 6);
  const int lane = threadIdx.x & 63;
  const int g8 = lane >> 3;   // edge subgroup 0..7
  const int l8 = lane & 7;    // channel chunk: channels l8*16 .. l8*16+15
  const u32x4* __restrict__ xw4 = (const u32x4*)xwq;  // 8 u32x4 per row

  for (int wid = wid0; wid < n; wid += nwaves) {
    const int start = row_ptr[wid], end = row_ptr[wid + 1];

    float acc[16];
#pragma unroll
    for (int j = 0; j < 16; ++j) acc[j] = 0.f;
    float S = 0.f;  // per-lane sum of vp over owned edges (offset correction)

    for (int e0 = start; e0 < end; e0 += 64) {
      // each lane owns one edge: coalesced meta + one scale gather / 64 edges
      const int e = e0 + lane;
      int   c_my = 0;
      float vp_my = 0.f;
      if (e < end) {
        c_my = __builtin_nontemporal_load(edge_col + e);
        const float v = __builtin_nontemporal_load(edge_val + e);
        vp_my = v * scale[c_my];
      }
      S += vp_my;

      // sub-iter it covers edges e0+it*8 .. e0+it*8+7; wave-uniform early exit
#pragma unroll
      for (int it = 0; it < 8; ++it) {
        if (e0 + it * 8 >= end) break;
        const int src  = it * 8 + g8;
        const int   c  = __shfl(c_my, src);
        const float vp = __shfl(vp_my, src);
        const u32x4 u = xw4[c * 8 + l8];
        ACC16(u, vp);
      }
    }

    // reduce S over all 64 lanes (each lane owned distinct edges)
    S += __shfl_xor(S, 1);
    S += __shfl_xor(S, 2);
    S += __shfl_xor(S, 4);
    S += __shfl_xor(S, 8);
    S += __shfl_xor(S, 16);
    S += __shfl_xor(S, 32);

    // sum the 8 edge-subgroups' partials (lanes differing in bits 3,4,5)
#pragma unroll
    for (int j = 0; j < 16; ++j) {
      acc[j] += __shfl_xor(acc[j], 8);
      acc[j] += __shfl_xor(acc[j], 16);
      acc[j] += __shfl_xor(acc[j], 32);
    }

    if (g8 == 0) {
      const int c = l8 * 16;
      const float off = 128.f * S;
#pragma unroll
      for (int q = 0; q < 4; ++q) {
        const f32x4 bv = *(const f32x4*)&bias[c + q * 4];
        f32x4 o;
        o[0] = fmaxf(acc[q * 4 + 0] - off + bv[0], 0.f);
        o[1] = fmaxf(acc[q * 4 + 1] - off + bv[1], 0.f);
        o[2] = fmaxf(acc[q * 4 + 2] - off + bv[2], 0.f);
        o[3] = fmaxf(acc[q * 4 + 3] - off + bv[3], 0.f);
        __builtin_nontemporal_store(o, (f32x4*)&out[(size_t)wid * CH + c + q * 4]);
      }
    }
  }
}

extern "C" void kernel_launch(void* const* d_in, const int* in_sizes, int n_in,
                              void* d_out, int out_size, void* d_ws, size_t ws_size,
                              hipStream_t stream) {
  const float* x        = (const float*)d_in[0];
  const float* kernel   = (const float*)d_in[1];
  const float* bias     = (const float*)d_in[2];
  const float* edge_val = (const float*)d_in[3];
  const int*   edge_row = (const int*)d_in[4];
  const int*   edge_col = (const int*)d_in[5];
  float* out = (float*)d_out;

  const int n       = in_sizes[0] / F_IN;   // 100000
  const int n_edges = in_sizes[3];          // 3200000

  // ws layout: [xwq: n*CH int8 = 12.8 MB][scale: n f32][row_ptr: (n+1) int]
  unsigned char* xwq = (unsigned char*)d_ws;
  float* scale = (float*)((char*)d_ws + (size_t)n * CH);
  int* rowptr  = (int*)((char*)d_ws + (size_t)n * CH + (size_t)n * sizeof(float));

  // Phase 1 (fused): XW = X @ W (bf16 MFMA) + int8 quant + CSR row_ptr
  const int GB = (n + 127) / 128;
  const int RB = (n + 1 + 511) / 512;
  gemm_rowptr_fused<<<GB + RB, 512, 0, stream>>>(x, kernel, xwq, scale,
                                                 edge_row, rowptr,
                                                 n, n_edges, GB);

  // Phase 2: SpMM + bias + ReLU. Grid-stride: 2048 blocks = 8 blocks/CU.
  spmm_rowwave<<<2048, 256, 0, stream>>>(xwq, scale, edge_val, edge_col,
                                         rowptr, bias, out, n);
}

// Round 5
// 127.290 us; speedup vs baseline: 1.2175x; 1.2175x over previous
//
#include <hip/hip_runtime.h>

#define F_IN 128
#define CH   128

typedef __attribute__((ext_vector_type(8))) short bf16x8;
typedef __attribute__((ext_vector_type(4))) float f32x4;
typedef __attribute__((ext_vector_type(2))) float f32x2;
typedef __attribute__((ext_vector_type(4))) unsigned u32x4;

// f32 -> bf16 round-to-nearest-even
static __device__ __forceinline__ ushort f2b(float f) {
  union { float f; unsigned u; } v; v.f = f;
  const unsigned u = v.u;
  return (ushort)((u + 0x7FFFu + ((u >> 16) & 1u)) >> 16);
}

// ---------------------------------------------------------------------------
// Phase 1 (fused): blocks [0, gemm_blocks) do XW = X @ W via bf16 MFMA,
//   then quantize each output row to int8 (offset-binary, per-node scale
//   s[r] = rowmax/127) -> 12.8 MB table + 400 KB scales.
// blocks [gemm_blocks, ...) do row_ptr[r] = lower_bound(edge_row, r).
// mfma_f32_16x16x32_bf16 layouts (guide §3, m89-verified):
//   A frag: row = lane&15, k = (lane>>4)*8 + j
//   B frag: col = lane&15, k = (lane>>4)*8 + j
//   C/D   : col = lane&15, row = (lane>>4)*4 + reg
// ---------------------------------------------------------------------------
__global__ __launch_bounds__(512) void gemm_rowptr_fused(
    const float* __restrict__ x, const float* __restrict__ w,
    unsigned char* __restrict__ xwq, float* __restrict__ scale,
    const int* __restrict__ edge_row, int* __restrict__ row_ptr,
    int n, int n_edges, int gemm_blocks) {
  __shared__ __align__(16) ushort Wt[F_IN * CH];  // W^T, swizzled, 32 KB
  const int t = threadIdx.x;

  if ((int)blockIdx.x >= gemm_blocks) {
    // ---- rowptr tail blocks: CSR offsets from sorted edge_row ----
    const int r = ((int)blockIdx.x - gemm_blocks) * 512 + t;
    if (r <= n) {
      int lo = 0, hi = n_edges;
      while (lo < hi) {
        const int mid = (lo + hi) >> 1;
        if (edge_row[mid] < r) lo = mid + 1; else hi = mid;
      }
      row_ptr[r] = lo;
    }
    return;
  }

  // ---- GEMM blocks ----
  // stage W^T as bf16 with XOR swizzle: byte ^= (col&7)<<4
  for (int i = t; i < (F_IN * CH) / 4; i += 512) {
    const int k  = i >> 5;          // 0..127
    const int n4 = (i & 31) << 2;   // 0,4,...,124
    const f32x4 wv = *(const f32x4*)&w[k * CH + n4];
#pragma unroll
    for (int q = 0; q < 4; ++q) {
      const int nn = n4 + q;
      const int byte = (nn * 256 + k * 2) ^ ((nn & 7) << 4);
      *(ushort*)((char*)Wt + byte) = f2b(wv[q]);
    }
  }
  __syncthreads();

  const int wave = t >> 6, lane = t & 63;
  const int R0   = blockIdx.x * 128 + wave * 16;
  const int arow = R0 + (lane & 15);
  const int kgrp = (lane >> 4) * 8;

  // A fragments (4 K-steps), f32->bf16 in-register; x is read-once -> nt loads
  bf16x8 a[4];
#pragma unroll
  for (int s = 0; s < 4; ++s) {
    if (arow < n) {
      const f32x4 p0 = __builtin_nontemporal_load(
          (const f32x4*)&x[arow * F_IN + s * 32 + kgrp]);
      const f32x4 p1 = __builtin_nontemporal_load(
          (const f32x4*)&x[arow * F_IN + s * 32 + kgrp + 4]);
#pragma unroll
      for (int j = 0; j < 4; ++j) {
        a[s][j]     = (short)f2b(p0[j]);
        a[s][j + 4] = (short)f2b(p1[j]);
      }
    } else {
#pragma unroll
      for (int j = 0; j < 8; ++j) a[s][j] = (short)0;
    }
  }

  f32x4 acc[8];
#pragma unroll
  for (int t8 = 0; t8 < 8; ++t8) acc[t8] = (f32x4){0.f, 0.f, 0.f, 0.f};

#pragma unroll
  for (int t8 = 0; t8 < 8; ++t8) {
    const int col = t8 * 16 + (lane & 15);
#pragma unroll
    for (int s = 0; s < 4; ++s) {
      const int byte = (col * 256 + (s * 32 + kgrp) * 2) ^ ((col & 7) << 4);
      const bf16x8 b = *(const bf16x8*)((const char*)Wt + byte);
      acc[t8] = __builtin_amdgcn_mfma_f32_16x16x32_bf16(a[s], b, acc[t8], 0, 0, 0);
    }
  }

  // Epilogue: per-row absmax (shfl over the 16 channel-lanes) -> int8 quant.
  const int li = lane & 15;
  const int r0 = R0 + (lane >> 4) * 4;
#pragma unroll
  for (int i = 0; i < 4; ++i) {
    const int rr = r0 + i;
    float m = 0.f;
#pragma unroll
    for (int t8 = 0; t8 < 8; ++t8) m = fmaxf(m, fabsf(acc[t8][i]));
    m = fmaxf(m, __shfl_xor(m, 1));
    m = fmaxf(m, __shfl_xor(m, 2));
    m = fmaxf(m, __shfl_xor(m, 4));
    m = fmaxf(m, __shfl_xor(m, 8));
    const float inv = (m > 1e-20f) ? 127.f / m : 0.f;
    if (rr < n) {
      if (li == 0) scale[rr] = m * (1.f / 127.f);
#pragma unroll
      for (int t8 = 0; t8 < 8; ++t8) {
        // |acc|*inv <= 127 by construction; +128 -> [1,255], no clamp needed
        const float q = rintf(acc[t8][i] * inv) + 128.f;
        xwq[rr * CH + t8 * 16 + li] = (unsigned char)q;
      }
    }
  }
}

// ---------------------------------------------------------------------------
// Phase 2: SpMM on the int8 table. One wave per row (CSR), 25K blocks
// (R3 launch — grid-stride falsified in R4). 64-edge superblock.
// Key structure (R4 lesson): gathers and ACC are SPLIT into separate
// unconditional / early-exit regions:
//   * 8 gathers batch-issue unconditionally into u[8] (8-deep MLP preserved;
//     dummy slots gather hot row 0 — nearly free, R3-proven).
//   * ACC loop breaks wave-uniformly when slots are exhausted (mean degree
//     32 -> ~45% of decode VALU skipped, without touching the memory stream).
//   * decode uses f32x2 elementwise fma -> v_pk_fma_f32 (dual-issue f32),
//     halving FMA instruction count.
// Meta: each lane owns ONE edge (2 coalesced loads + 1 scale gather / 64
// edges); vp = val*scale[col] distributed via __shfl. -128 offset folded
// into scalar S. Butterfly over the 8 edge-subgroups (xor 8/16/32) at end.
// ---------------------------------------------------------------------------
#define ACCD(word, j0)                                                  \
  do {                                                                  \
    f32x2 lo, hi;                                                       \
    lo[0] = (float)((word) & 0xFFu);                                    \
    lo[1] = (float)(((word) >> 8) & 0xFFu);                             \
    hi[0] = (float)(((word) >> 16) & 0xFFu);                            \
    hi[1] = (float)((word) >> 24);                                      \
    acc2[(j0)]     = __builtin_elementwise_fma(vv, lo, acc2[(j0)]);     \
    acc2[(j0) + 1] = __builtin_elementwise_fma(vv, hi, acc2[(j0) + 1]); \
  } while (0)

#define ACC16PK(U, V)                                                   \
  do {                                                                  \
    const f32x2 vv = {(V), (V)};                                        \
    ACCD((U)[0], 0);                                                    \
    ACCD((U)[1], 2);                                                    \
    ACCD((U)[2], 4);                                                    \
    ACCD((U)[3], 6);                                                    \
  } while (0)

__global__ __launch_bounds__(256) void spmm_rowwave(
    const unsigned char* __restrict__ xwq, const float* __restrict__ scale,
    const float* __restrict__ edge_val, const int* __restrict__ edge_col,
    const int* __restrict__ row_ptr, const float* __restrict__ bias,
    float* __restrict__ out, int n) {
  const int wid = (int)((blockIdx.x * blockDim.x + threadIdx.x) >> 6);
  if (wid >= n) return;
  const int lane = threadIdx.x & 63;
  const int g8 = lane >> 3;   // edge subgroup 0..7
  const int l8 = lane & 7;    // channel chunk: channels l8*16 .. l8*16+15
  const int start = row_ptr[wid], end = row_ptr[wid + 1];
  const u32x4* __restrict__ xw4 = (const u32x4*)xwq;  // 8 u32x4 per row

  f32x2 acc2[8];
#pragma unroll
  for (int j = 0; j < 8; ++j) acc2[j] = (f32x2){0.f, 0.f};
  float S = 0.f;  // per-lane sum of vp over owned edges (offset correction)

  for (int e0 = start; e0 < end; e0 += 64) {
    // each lane owns one edge: coalesced meta + one scale gather / 64 edges
    const int e = e0 + lane;
    int   c_my = 0;
    float vp_my = 0.f;
    if (e < end) {
      c_my = __builtin_nontemporal_load(edge_col + e);
      const float v = __builtin_nontemporal_load(edge_val + e);
      vp_my = v * scale[c_my];
    }
    S += vp_my;

    // --- unconditional batched gather region: 8-deep MLP, no branches ---
    u32x4 u[8];
    float vp[8];
#pragma unroll
    for (int it = 0; it < 8; ++it) {
      const int src = it * 8 + g8;
      const int c   = __shfl(c_my, src);
      vp[it] = __shfl(vp_my, src);
      u[it]  = xw4[c * 8 + l8];
    }

    // --- ACC region: wave-uniform early exit skips dummy-slot decode ---
#pragma unroll
    for (int it = 0; it < 8; ++it) {
      if (e0 + it * 8 >= end) break;
      ACC16PK(u[it], vp[it]);
    }
  }

  // reduce S over all 64 lanes (each lane owned distinct edges)
  S += __shfl_xor(S, 1);
  S += __shfl_xor(S, 2);
  S += __shfl_xor(S, 4);
  S += __shfl_xor(S, 8);
  S += __shfl_xor(S, 16);
  S += __shfl_xor(S, 32);

  // sum the 8 edge-subgroups' partials (lanes differing in bits 3,4,5)
  float* acc = (float*)acc2;
#pragma unroll
  for (int j = 0; j < 16; ++j) {
    acc[j] += __shfl_xor(acc[j], 8);
    acc[j] += __shfl_xor(acc[j], 16);
    acc[j] += __shfl_xor(acc[j], 32);
  }

  if (g8 == 0) {
    const int c = l8 * 16;
    const float off = 128.f * S;
#pragma unroll
    for (int q = 0; q < 4; ++q) {
      const f32x4 bv = *(const f32x4*)&bias[c + q * 4];
      f32x4 o;
      o[0] = fmaxf(acc[q * 4 + 0] - off + bv[0], 0.f);
      o[1] = fmaxf(acc[q * 4 + 1] - off + bv[1], 0.f);
      o[2] = fmaxf(acc[q * 4 + 2] - off + bv[2], 0.f);
      o[3] = fmaxf(acc[q * 4 + 3] - off + bv[3], 0.f);
      __builtin_nontemporal_store(o, (f32x4*)&out[(size_t)wid * CH + c + q * 4]);
    }
  }
}

extern "C" void kernel_launch(void* const* d_in, const int* in_sizes, int n_in,
                              void* d_out, int out_size, void* d_ws, size_t ws_size,
                              hipStream_t stream) {
  const float* x        = (const float*)d_in[0];
  const float* kernel   = (const float*)d_in[1];
  const float* bias     = (const float*)d_in[2];
  const float* edge_val = (const float*)d_in[3];
  const int*   edge_row = (const int*)d_in[4];
  const int*   edge_col = (const int*)d_in[5];
  float* out = (float*)d_out;

  const int n       = in_sizes[0] / F_IN;   // 100000
  const int n_edges = in_sizes[3];          // 3200000

  // ws layout: [xwq: n*CH int8 = 12.8 MB][scale: n f32][row_ptr: (n+1) int]
  unsigned char* xwq = (unsigned char*)d_ws;
  float* scale = (float*)((char*)d_ws + (size_t)n * CH);
  int* rowptr  = (int*)((char*)d_ws + (size_t)n * CH + (size_t)n * sizeof(float));

  // Phase 1 (fused): XW = X @ W (bf16 MFMA) + int8 quant + CSR row_ptr
  const int GB = (n + 127) / 128;
  const int RB = (n + 1 + 511) / 512;
  gemm_rowptr_fused<<<GB + RB, 512, 0, stream>>>(x, kernel, xwq, scale,
                                                 edge_row, rowptr,
                                                 n, n_edges, GB);

  // Phase 2: SpMM + bias + ReLU (one wave per row, no atomics; R3 launch)
  spmm_rowwave<<<(n + 3) / 4, 256, 0, stream>>>(xwq, scale, edge_val, edge_col,
                                                rowptr, bias, out, n);
}